// Round 2
// baseline (997.252 us; speedup 1.0000x reference)
//
#include <hip/hip_runtime.h>

// T=2^21 sequential nonlinear storage recurrence + per-column z-score.
// Contractive recurrence -> chunked scan with redundant warm-up (W=1024,
// proven absmax 0.031 << 0.175). Latency attack: ILP=8 independent chunks
// interleaved per lane -> dependent-chain latency (~330cy/step measured)
// hidden behind issue (~70cy/chain-step).

#define T_TOTAL  (1 << 21)
#define L_CHUNK  128
#define W_WARM   1024
#define STEPS    (W_WARM + L_CHUNK)          // 1152
#define C_CHUNKS (T_TOTAL / L_CHUNK)         // 16384
#define ILP      8                           // chains per lane
#define PF       2                           // prefetch lead (iterations)
#define N_LANES  (C_CHUNKS / ILP)            // 2048
#define N_BLOCKS (N_LANES / 64)              // 32 blocks -> 32 CUs, 1 wave each

__global__ __launch_bounds__(64) void scan_kernel(const float2* __restrict__ xp,
                                                  const float* __restrict__ x1p,
                                                  float* __restrict__ out,
                                                  double* __restrict__ stats) {
    const float x1s    = x1p[0];
    const float inv_x1 = 1.0f / x1s;
    const float c449   = (4.0f / 9.0f) * inv_x1;

    const int g = blockIdx.x * 64 + threadIdx.x;   // global lane id

    int   tb[ILP];
    float s[ILP];
    float2 buf[ILP][PF];
#pragma unroll
    for (int c = 0; c < ILP; ++c) {
        int k = g * ILP + c;                       // chunk id
        tb[c] = k * L_CHUNK - W_WARM;
        s[c]  = 0.0f;
#pragma unroll
        for (int jj = 0; jj < PF; ++jj) {
            int tl = min(max(tb[c] + jj, 0), T_TOTAL - 1);
            buf[c][jj] = xp[tl];
        }
    }

    float sum0 = 0, sum1 = 0, sum2 = 0, sum3 = 0, sum4 = 0, sum5 = 0;
    float sq0 = 0, sq1 = 0, sq2 = 0, sq3 = 0, sq4 = 0, sq5 = 0;

    for (int j = 0; j < STEPS; j += PF) {
#pragma unroll
        for (int jj = 0; jj < PF; ++jj) {
            const bool emit = (j + jj) >= W_WARM;  // uniform across lanes/chains
#pragma unroll
            for (int c = 0; c < ILP; ++c) {
                const int t = tb[c] + j + jj;
                float2 d = buf[c][jj];
                // prefetch this slot for step j+jj+PF
                int tl = min(max(t + PF, 0), T_TOTAL - 1);
                buf[c][jj] = xp[tl];

                float pn = fmaxf(d.x - d.y, 0.0f);
                float en = fmaxf(d.y - d.x, 0.0f);
                if (t < 0) { pn = 0.0f; en = 0.0f; }   // identity while s==0

                // off-chain (depends only on inputs): tanh(x), |x|<=0.0286
                float xpn = pn * inv_x1, xen = en * inv_x1;
                float tp = xpn * fmaf(xpn * xpn, -0.33333334f, 1.0f);
                float te = xen * fmaf(xen * xen, -0.33333334f, 1.0f);
                float xtp = x1s * tp;
                float ote = 1.0f + te;

                // dependent chain on s[c]
                float sc  = s[c];
                float r   = sc * inv_x1;
                float d1  = fmaf(r, tp, 1.0f);
                float rc1 = __builtin_amdgcn_rcpf(d1);
                float a   = fmaf(-r, r, 1.0f);
                float p_s = xtp * (a * rc1);
                float d2  = fmaf(-te, r, ote);
                float rc2 = __builtin_amdgcn_rcpf(d2);
                float e_s = (sc * (2.0f - r)) * (te * rc2);
                float s1  = sc + (p_s - e_s);
                float y   = s1 * c449;
                float y2  = y * y;
                float tq  = fmaf(y2, y2, 1.0f);
                float rs  = __builtin_amdgcn_rsqf(__builtin_amdgcn_sqrtf(tq)); // tq^-1/4
                float s2  = s1 * rs;
                float perc = s1 - s2;
                s[c] = s2;

                if (emit) {
                    *(float2*)(out + 6 * (size_t)t + 4) = make_float2(p_s, perc);
                    sum0 += d.x;  sq0 = fmaf(d.x, d.x, sq0);
                    sum1 += d.y;  sq1 = fmaf(d.y, d.y, sq1);
                    sum2 += pn;   sq2 = fmaf(pn, pn, sq2);
                    sum3 += en;   sq3 = fmaf(en, en, sq3);
                    sum4 += p_s;  sq4 = fmaf(p_s, p_s, sq4);
                    sum5 += perc; sq5 = fmaf(perc, perc, sq5);
                }
            }
        }
    }

    double v[12] = {sum0, sum1, sum2, sum3, sum4, sum5,
                    sq0, sq1, sq2, sq3, sq4, sq5};
#pragma unroll
    for (int c = 0; c < 12; ++c) {
        double val = v[c];
        for (int off = 32; off > 0; off >>= 1)
            val += __shfl_down(val, off, 64);
        if (threadIdx.x == 0) atomicAdd(&stats[c], val);
    }
}

__global__ void finalize_stats(const double* __restrict__ stats,
                               float* __restrict__ musig) {
    int c = threadIdx.x;
    if (c < 6) {
        double sum = stats[c], sumsq = stats[6 + c];
        double n = (double)T_TOTAL;
        double mu = sum / n;
        double var = (sumsq - sum * sum / n) / (n - 1.0);
        double sig = sqrt(var);
        musig[c] = (float)mu;
        musig[6 + c] = (float)(1.0 / sig);
    }
}

__global__ __launch_bounds__(256) void normalize_kernel(const float4* __restrict__ xp4,
                                                        float* __restrict__ out,
                                                        const float* __restrict__ musig) {
    float mu[6], is[6];
#pragma unroll
    for (int c = 0; c < 6; ++c) { mu[c] = musig[c]; is[c] = musig[6 + c]; }

    int idx = blockIdx.x * blockDim.x + threadIdx.x;
    int stride = gridDim.x * blockDim.x;
    for (int p = idx; p < T_TOTAL / 2; p += stride) {
        float4 xv = xp4[p];                         // rows 2p, 2p+1
        float* o = out + 12 * (size_t)p;
        float2 pp0 = *(const float2*)(o + 4);       // p_s, perc of row 2p
        float2 pp1 = *(const float2*)(o + 10);      // p_s, perc of row 2p+1
        float pn0 = fmaxf(xv.x - xv.y, 0.0f), en0 = fmaxf(xv.y - xv.x, 0.0f);
        float pn1 = fmaxf(xv.z - xv.w, 0.0f), en1 = fmaxf(xv.w - xv.z, 0.0f);
        float4 o0 = {(xv.x - mu[0]) * is[0], (xv.y - mu[1]) * is[1],
                     (pn0 - mu[2]) * is[2], (en0 - mu[3]) * is[3]};
        float4 o1 = {(pp0.x - mu[4]) * is[4], (pp0.y - mu[5]) * is[5],
                     (xv.z - mu[0]) * is[0], (xv.w - mu[1]) * is[1]};
        float4 o2 = {(pn1 - mu[2]) * is[2], (en1 - mu[3]) * is[3],
                     (pp1.x - mu[4]) * is[4], (pp1.y - mu[5]) * is[5]};
        *(float4*)(o + 0) = o0;
        *(float4*)(o + 4) = o1;
        *(float4*)(o + 8) = o2;
    }
}

extern "C" void kernel_launch(void* const* d_in, const int* in_sizes, int n_in,
                              void* d_out, int out_size, void* d_ws, size_t ws_size,
                              hipStream_t stream) {
    const float2* x = (const float2*)d_in[0];
    const float* x1 = (const float*)d_in[1];
    float* out = (float*)d_out;
    double* stats = (double*)d_ws;
    float* musig = (float*)((char*)d_ws + 12 * sizeof(double));

    hipMemsetAsync(d_ws, 0, 12 * sizeof(double), stream);
    scan_kernel<<<N_BLOCKS, 64, 0, stream>>>(x, x1, out, stats);
    finalize_stats<<<1, 64, 0, stream>>>(stats, musig);
    normalize_kernel<<<2048, 256, 0, stream>>>((const float4*)x, out, musig);
}

// Round 3
// 120.116 us; speedup vs baseline: 8.3024x; 8.3024x over previous
//
#include <hip/hip_runtime.h>

// T=2^21 sequential nonlinear storage recurrence + per-column z-score.
// Contractive recurrence -> chunked scan with redundant warm-up.
// R3: W=512 (absmax floor 0.031 is fp32 noise, not truncation), 1 chain/lane,
// 256 waves (1/CU). Spill fix: __launch_bounds__(64,1) + prefetch pipeline in
// NAMED float4 regs (R1/R2 had VGPR_Count=44 with >60 live floats -> scratch
// round-trip ~250cy/step was the whole stall).

#define T_TOTAL  (1 << 21)
#define L_CHUNK  128
#define W_WARM   512
#define STEPS    (W_WARM + L_CHUNK)          // 640
#define C_CHUNKS (T_TOTAL / L_CHUNK)         // 16384
#define N_BLOCKS (C_CHUNKS / 64)             // 256 blocks -> 1 wave/CU

// one recurrence step; EMIT/MASK are compile-time per loop phase
#define STEP(dx, dy, EMIT, MASK, tcur)                                        \
    {                                                                         \
        float pn = fmaxf((dx) - (dy), 0.0f);                                  \
        float en = fmaxf((dy) - (dx), 0.0f);                                  \
        if (MASK) {                                                           \
            if ((tcur) < 0) { pn = 0.0f; en = 0.0f; }                         \
        }                                                                     \
        float xpn = pn * inv_x1, xen = en * inv_x1;                           \
        float tp = xpn * fmaf(xpn * xpn, -0.33333334f, 1.0f);                 \
        float te = xen * fmaf(xen * xen, -0.33333334f, 1.0f);                 \
        float r   = s * inv_x1;                                               \
        float d1  = fmaf(r, tp, 1.0f);                                        \
        float rc1 = __builtin_amdgcn_rcpf(d1);                                \
        float a   = fmaf(-r, r, 1.0f);                                        \
        float p_s = (x1s * tp) * (a * rc1);                                   \
        float d2  = fmaf(-te, r, 1.0f + te);                                  \
        float rc2 = __builtin_amdgcn_rcpf(d2);                                \
        float e_s = (s * (2.0f - r)) * (te * rc2);                            \
        float s1  = s + (p_s - e_s);                                          \
        float y   = s1 * c449;                                                \
        float y2  = y * y;                                                    \
        float tq  = fmaf(y2, y2, 1.0f);                                       \
        float rs  = __builtin_amdgcn_rsqf(__builtin_amdgcn_sqrtf(tq));        \
        float s2  = s1 * rs;                                                  \
        if (EMIT) {                                                           \
            float perc = s1 - s2;                                             \
            *(float2*)(out + 6 * (size_t)(tcur) + 4) = make_float2(p_s, perc);\
            sum0 += (dx);  sq0 = fmaf((dx), (dx), sq0);                       \
            sum1 += (dy);  sq1 = fmaf((dy), (dy), sq1);                       \
            sum2 += pn;    sq2 = fmaf(pn, pn, sq2);                           \
            sum3 += en;    sq3 = fmaf(en, en, sq3);                           \
            sum4 += p_s;   sq4 = fmaf(p_s, p_s, sq4);                         \
            sum5 += perc;  sq5 = fmaf(perc, perc, sq5);                       \
        }                                                                     \
        s = s2;                                                               \
    }

// 8 steps per group; 4 named float4 prefetch buffers, ~7-step (≈500cy) lead
#define GROUP(EMIT, MASK, tg)                                                 \
    {                                                                         \
        STEP(bufA.x, bufA.y, EMIT, MASK, (tg) + 0);                           \
        STEP(bufA.z, bufA.w, EMIT, MASK, (tg) + 1);                           \
        bufA = ld4((tg) + 8);                                                 \
        STEP(bufB.x, bufB.y, EMIT, MASK, (tg) + 2);                           \
        STEP(bufB.z, bufB.w, EMIT, MASK, (tg) + 3);                           \
        bufB = ld4((tg) + 10);                                                \
        STEP(bufC.x, bufC.y, EMIT, MASK, (tg) + 4);                           \
        STEP(bufC.z, bufC.w, EMIT, MASK, (tg) + 5);                           \
        bufC = ld4((tg) + 12);                                                \
        STEP(bufD.x, bufD.y, EMIT, MASK, (tg) + 6);                           \
        STEP(bufD.z, bufD.w, EMIT, MASK, (tg) + 7);                           \
        bufD = ld4((tg) + 14);                                                \
    }

__global__ __launch_bounds__(64, 1) void scan_kernel(const float2* __restrict__ xp,
                                                     const float* __restrict__ x1p,
                                                     float* __restrict__ out,
                                                     double* __restrict__ stats) {
    const float x1s    = x1p[0];
    const float inv_x1 = 1.0f / x1s;
    const float c449   = (4.0f / 9.0f) * inv_x1;
    const float4* __restrict__ xp4 = (const float4*)xp;

    const int k  = blockIdx.x * 64 + threadIdx.x;  // chunk id
    const int t0 = k * L_CHUNK - W_WARM;           // even

    auto ld4 = [&](int tt) -> float4 {
        int tc = min(max(tt, 0), T_TOTAL - 2);     // tt even -> tc even
        return xp4[tc >> 1];
    };

    float4 bufA = ld4(t0 + 0);
    float4 bufB = ld4(t0 + 2);
    float4 bufC = ld4(t0 + 4);
    float4 bufD = ld4(t0 + 6);

    float s = 0.0f;
    float sum0 = 0, sum1 = 0, sum2 = 0, sum3 = 0, sum4 = 0, sum5 = 0;
    float sq0 = 0, sq1 = 0, sq2 = 0, sq3 = 0, sq4 = 0, sq5 = 0;

#pragma unroll 1
    for (int j = 0; j < W_WARM; j += 8) {          // warm phase: no emit
        const int tg = t0 + j;
        GROUP(false, true, tg)
    }
#pragma unroll 1
    for (int j = W_WARM; j < STEPS; j += 8) {      // emit phase: t >= 0 always
        const int tg = t0 + j;
        GROUP(true, false, tg)
    }

    double v[12] = {sum0, sum1, sum2, sum3, sum4, sum5,
                    sq0, sq1, sq2, sq3, sq4, sq5};
#pragma unroll
    for (int c = 0; c < 12; ++c) {
        double val = v[c];
        for (int off = 32; off > 0; off >>= 1)
            val += __shfl_down(val, off, 64);
        if (threadIdx.x == 0) atomicAdd(&stats[c], val);
    }
}

__global__ void finalize_stats(const double* __restrict__ stats,
                               float* __restrict__ musig) {
    int c = threadIdx.x;
    if (c < 6) {
        double sum = stats[c], sumsq = stats[6 + c];
        double n = (double)T_TOTAL;
        double mu = sum / n;
        double var = (sumsq - sum * sum / n) / (n - 1.0);
        double sig = sqrt(var);
        musig[c] = (float)mu;
        musig[6 + c] = (float)(1.0 / sig);
    }
}

__global__ __launch_bounds__(256) void normalize_kernel(const float4* __restrict__ xp4,
                                                        float* __restrict__ out,
                                                        const float* __restrict__ musig) {
    float mu[6], is[6];
#pragma unroll
    for (int c = 0; c < 6; ++c) { mu[c] = musig[c]; is[c] = musig[6 + c]; }

    int idx = blockIdx.x * blockDim.x + threadIdx.x;
    int stride = gridDim.x * blockDim.x;
    for (int p = idx; p < T_TOTAL / 2; p += stride) {
        float4 xv = xp4[p];                         // rows 2p, 2p+1
        float* o = out + 12 * (size_t)p;
        float2 pp0 = *(const float2*)(o + 4);       // p_s, perc of row 2p
        float2 pp1 = *(const float2*)(o + 10);      // p_s, perc of row 2p+1
        float pn0 = fmaxf(xv.x - xv.y, 0.0f), en0 = fmaxf(xv.y - xv.x, 0.0f);
        float pn1 = fmaxf(xv.z - xv.w, 0.0f), en1 = fmaxf(xv.w - xv.z, 0.0f);
        float4 o0 = {(xv.x - mu[0]) * is[0], (xv.y - mu[1]) * is[1],
                     (pn0 - mu[2]) * is[2], (en0 - mu[3]) * is[3]};
        float4 o1 = {(pp0.x - mu[4]) * is[4], (pp0.y - mu[5]) * is[5],
                     (xv.z - mu[0]) * is[0], (xv.w - mu[1]) * is[1]};
        float4 o2 = {(pn1 - mu[2]) * is[2], (en1 - mu[3]) * is[3],
                     (pp1.x - mu[4]) * is[4], (pp1.y - mu[5]) * is[5]};
        *(float4*)(o + 0) = o0;
        *(float4*)(o + 4) = o1;
        *(float4*)(o + 8) = o2;
    }
}

extern "C" void kernel_launch(void* const* d_in, const int* in_sizes, int n_in,
                              void* d_out, int out_size, void* d_ws, size_t ws_size,
                              hipStream_t stream) {
    const float2* x = (const float2*)d_in[0];
    const float* x1 = (const float*)d_in[1];
    float* out = (float*)d_out;
    double* stats = (double*)d_ws;
    float* musig = (float*)((char*)d_ws + 12 * sizeof(double));

    hipMemsetAsync(d_ws, 0, 12 * sizeof(double), stream);
    scan_kernel<<<N_BLOCKS, 64, 0, stream>>>(x, x1, out, stats);
    finalize_stats<<<1, 64, 0, stream>>>(stats, musig);
    normalize_kernel<<<2048, 256, 0, stream>>>((const float4*)x, out, musig);
}

// Round 4
// 105.868 us; speedup vs baseline: 9.4197x; 1.1346x over previous
//
#include <hip/hip_runtime.h>

// T=2^21 sequential nonlinear storage recurrence + per-column z-score.
// Chunked scan with redundant warm-up (W=512, L=128). R4: the ~200cy/step
// stall was transcendental latency on the serial chain (rcp x2, sqrt, rsq).
// All four replaced by short polynomials (args <= 0.04): pure-FMA chain,
// depth ~56cy. Stores packed (b128 / 2 steps) into a compact side buffer in
// d_ws; normalize reads it linearly. Prefetch lead 16 steps via 8 named bufs.

#define T_TOTAL  (1 << 21)
#define L_CHUNK  128
#define W_WARM   512
#define STEPS    (W_WARM + L_CHUNK)          // 640
#define C_CHUNKS (T_TOTAL / L_CHUNK)         // 16384
#define N_BLOCKS (C_CHUNKS / 64)             // 256 blocks, 1 wave/CU
#define SIDE_OFF 1024                        // byte offset of side buf in d_ws

// one recurrence step, pure FMA (no rcp/sqrt/rsq on the chain)
#define STEP(dx, dy, MASK, tcur, PS, PERC)                                    \
    {                                                                         \
        float pn = fmaxf((dx) - (dy), 0.0f);                                  \
        float en = fmaxf((dy) - (dx), 0.0f);                                  \
        if (MASK) { if ((tcur) < 0) { pn = 0.0f; en = 0.0f; } }               \
        float xpn = pn * inv_x1, xen = en * inv_x1;                           \
        float tp  = xpn * fmaf(xpn * xpn, -0.33333334f, 1.0f);                \
        float te  = xen * fmaf(xen * xen, -0.33333334f, 1.0f);                \
        float xtp = x1s * tp;                                                 \
        float r   = s * inv_x1;                                               \
        float e1  = r * tp;                                                   \
        float q1  = (1.0f - e1) * fmaf(e1, e1, 1.0f);   /* ~1/(1+e1) */       \
        float A   = xtp * fmaf(-r, r, 1.0f);                                  \
        float p_s = A * q1;                                                   \
        float omr = 1.0f - r;                                                 \
        float e2  = te * omr;                                                 \
        float q2  = (1.0f - e2) * fmaf(e2, e2, 1.0f);   /* ~1/(1+e2) */       \
        float B   = (s * (2.0f - r)) * te;                                    \
        float e_s = B * q2;                                                   \
        float s1  = s + (p_s - e_s);                                          \
        float y   = s1 * c449;                                                \
        float y2  = y * y;                                                    \
        float u   = y2 * y2;                                                  \
        float pl  = fmaf(u, fmaf(u, 0.1171875f, -0.15625f), 0.25f);           \
        float perc = (s1 * u) * pl;   /* s1*(1-(1+u)^-1/4), 3-term */         \
        s = s1 - perc;                                                        \
        PS = p_s; PERC = perc;                                                \
    }

#define ACCUM(dx, dy, p_s, perc)                                              \
    {                                                                         \
        float pn = fmaxf((dx) - (dy), 0.0f);                                  \
        float en = fmaxf((dy) - (dx), 0.0f);                                  \
        sum0 += (dx);  sq0 = fmaf((dx), (dx), sq0);                           \
        sum1 += (dy);  sq1 = fmaf((dy), (dy), sq1);                           \
        sum2 += pn;    sq2 = fmaf(pn, pn, sq2);                               \
        sum3 += en;    sq3 = fmaf(en, en, sq3);                               \
        sum4 += p_s;   sq4 = fmaf(p_s, p_s, sq4);                             \
        sum5 += perc;  sq5 = fmaf(perc, perc, sq5);                           \
    }

// two steps from one float4 buf; reload buf 16 steps ahead; optional emit
#define PAIR(BUF, EMIT, MASK, tp2)                                            \
    {                                                                         \
        float ps0, pc0, ps1, pc1;                                             \
        STEP(BUF.x, BUF.y, MASK, (tp2) + 0, ps0, pc0)                         \
        STEP(BUF.z, BUF.w, MASK, (tp2) + 1, ps1, pc1)                         \
        float4 dsave = BUF;                                                   \
        BUF = ld4((tp2) + 16);                                                \
        if (EMIT) {                                                           \
            if (SIDE) {                                                       \
                float4 o = {ps0, pc0, ps1, pc1};                              \
                *(float4*)(side + 2 * (size_t)(tp2)) = o;                     \
            } else {                                                          \
                *(float2*)(out + 6 * (size_t)(tp2) + 4)  = make_float2(ps0, pc0); \
                *(float2*)(out + 6 * (size_t)(tp2) + 10) = make_float2(ps1, pc1); \
            }                                                                 \
            ACCUM(dsave.x, dsave.y, ps0, pc0)                                 \
            ACCUM(dsave.z, dsave.w, ps1, pc1)                                 \
        }                                                                     \
    }

#define GROUP(EMIT, MASK, tg)                                                 \
    {                                                                         \
        PAIR(bufA, EMIT, MASK, (tg) + 0)                                      \
        PAIR(bufB, EMIT, MASK, (tg) + 2)                                      \
        PAIR(bufC, EMIT, MASK, (tg) + 4)                                      \
        PAIR(bufD, EMIT, MASK, (tg) + 6)                                      \
        PAIR(bufE, EMIT, MASK, (tg) + 8)                                      \
        PAIR(bufF, EMIT, MASK, (tg) + 10)                                     \
        PAIR(bufG, EMIT, MASK, (tg) + 12)                                     \
        PAIR(bufH, EMIT, MASK, (tg) + 14)                                     \
    }

template <bool SIDE>
__global__ __launch_bounds__(64, 1) void scan_kernel(const float2* __restrict__ xp,
                                                     const float* __restrict__ x1p,
                                                     float* __restrict__ out,
                                                     float* __restrict__ side,
                                                     double* __restrict__ stats) {
    const float x1s    = x1p[0];
    const float inv_x1 = 1.0f / x1s;
    const float c449   = (4.0f / 9.0f) * inv_x1;
    const float4* __restrict__ xp4 = (const float4*)xp;

    const int k  = blockIdx.x * 64 + threadIdx.x;  // chunk id
    const int t0 = k * L_CHUNK - W_WARM;           // even

    auto ld4 = [&](int tt) -> float4 {
        int tc = min(max(tt, 0), T_TOTAL - 2);     // tt even -> tc even
        return xp4[tc >> 1];
    };

    float4 bufA = ld4(t0 + 0),  bufB = ld4(t0 + 2);
    float4 bufC = ld4(t0 + 4),  bufD = ld4(t0 + 6);
    float4 bufE = ld4(t0 + 8),  bufF = ld4(t0 + 10);
    float4 bufG = ld4(t0 + 12), bufH = ld4(t0 + 14);

    float s = 0.0f;
    float sum0 = 0, sum1 = 0, sum2 = 0, sum3 = 0, sum4 = 0, sum5 = 0;
    float sq0 = 0, sq1 = 0, sq2 = 0, sq3 = 0, sq4 = 0, sq5 = 0;

#pragma unroll 1
    for (int j = 0; j < W_WARM; j += 16) {         // warm: no emit, t<0 mask
        const int tg = t0 + j;
        GROUP(false, true, tg)
    }
#pragma unroll 1
    for (int j = W_WARM; j < STEPS; j += 16) {     // emit: t >= 0 always
        const int tg = t0 + j;
        GROUP(true, false, tg)
    }

    double v[12] = {sum0, sum1, sum2, sum3, sum4, sum5,
                    sq0, sq1, sq2, sq3, sq4, sq5};
#pragma unroll
    for (int c = 0; c < 12; ++c) {
        double val = v[c];
        for (int off = 32; off > 0; off >>= 1)
            val += __shfl_down(val, off, 64);
        if (threadIdx.x == 0) atomicAdd(&stats[c], val);
    }
}

__global__ void finalize_stats(const double* __restrict__ stats,
                               float* __restrict__ musig) {
    int c = threadIdx.x;
    if (c < 6) {
        double sum = stats[c], sumsq = stats[6 + c];
        double n = (double)T_TOTAL;
        double mu = sum / n;
        double var = (sumsq - sum * sum / n) / (n - 1.0);
        double sig = sqrt(var);
        musig[c] = (float)mu;
        musig[6 + c] = (float)(1.0 / sig);
    }
}

template <bool SIDE>
__global__ __launch_bounds__(256) void normalize_kernel(const float4* __restrict__ xp4,
                                                        const float4* __restrict__ side4,
                                                        float* __restrict__ out,
                                                        const float* __restrict__ musig) {
    float mu[6], is[6];
#pragma unroll
    for (int c = 0; c < 6; ++c) { mu[c] = musig[c]; is[c] = musig[6 + c]; }

    int idx = blockIdx.x * blockDim.x + threadIdx.x;
    int stride = gridDim.x * blockDim.x;
    for (int p = idx; p < T_TOTAL / 2; p += stride) {
        float4 xv = xp4[p];                         // rows 2p, 2p+1
        float* o = out + 12 * (size_t)p;
        float4 sv;
        if (SIDE) {
            sv = side4[p];                          // {ps0,pc0,ps1,pc1} linear
        } else {
            float2 a = *(const float2*)(o + 4);
            float2 b = *(const float2*)(o + 10);
            sv = make_float4(a.x, a.y, b.x, b.y);
        }
        float pn0 = fmaxf(xv.x - xv.y, 0.0f), en0 = fmaxf(xv.y - xv.x, 0.0f);
        float pn1 = fmaxf(xv.z - xv.w, 0.0f), en1 = fmaxf(xv.w - xv.z, 0.0f);
        float4 o0 = {(xv.x - mu[0]) * is[0], (xv.y - mu[1]) * is[1],
                     (pn0 - mu[2]) * is[2], (en0 - mu[3]) * is[3]};
        float4 o1 = {(sv.x - mu[4]) * is[4], (sv.y - mu[5]) * is[5],
                     (xv.z - mu[0]) * is[0], (xv.w - mu[1]) * is[1]};
        float4 o2 = {(pn1 - mu[2]) * is[2], (en1 - mu[3]) * is[3],
                     (sv.z - mu[4]) * is[4], (sv.w - mu[5]) * is[5]};
        *(float4*)(o + 0) = o0;
        *(float4*)(o + 4) = o1;
        *(float4*)(o + 8) = o2;
    }
}

extern "C" void kernel_launch(void* const* d_in, const int* in_sizes, int n_in,
                              void* d_out, int out_size, void* d_ws, size_t ws_size,
                              hipStream_t stream) {
    const float2* x = (const float2*)d_in[0];
    const float* x1 = (const float*)d_in[1];
    float* out = (float*)d_out;
    double* stats = (double*)d_ws;
    float* musig = (float*)((char*)d_ws + 12 * sizeof(double));
    float* side  = (float*)((char*)d_ws + SIDE_OFF);

    const bool use_side = ws_size >= (size_t)SIDE_OFF + (size_t)T_TOTAL * 8;

    hipMemsetAsync(d_ws, 0, 12 * sizeof(double), stream);
    if (use_side) {
        scan_kernel<true><<<N_BLOCKS, 64, 0, stream>>>(x, x1, out, side, stats);
        finalize_stats<<<1, 64, 0, stream>>>(stats, musig);
        normalize_kernel<true><<<2048, 256, 0, stream>>>((const float4*)x,
                                                         (const float4*)side, out, musig);
    } else {
        scan_kernel<false><<<N_BLOCKS, 64, 0, stream>>>(x, x1, out, side, stats);
        finalize_stats<<<1, 64, 0, stream>>>(stats, musig);
        normalize_kernel<false><<<2048, 256, 0, stream>>>((const float4*)x,
                                                          (const float4*)side, out, musig);
    }
}